// Round 3
// baseline (1278.795 us; speedup 1.0000x reference)
//
#include <hip/hip_runtime.h>
#include <math.h>

// ---------------- stats (per-image 15 features, f64) ----------------
__global__ __launch_bounds__(256) void stats_kernel(const float* __restrict__ img,
                                                    double* __restrict__ feats)
{
    int b = blockIdx.x, tid = threadIdx.x;
    const float* r0 = img + (size_t)b * 3 * 65536;
    const float* g0 = r0 + 65536;
    const float* b0 = r0 + 131072;
    double s0=0,s1=0,s2=0, q0=0,q1=0,q2=0, l1=0,l2=0,l3=0,l4=0;
    float mn0=1e30f,mn1=1e30f,mn2=1e30f, mx0=-1e30f,mx1=-1e30f,mx2=-1e30f;
    double dark=0.0;
    for (int p = tid; p < 65536; p += 256) {
        float r = r0[p], g = g0[p], bl = b0[p];
        double rd_=r, gd=g, bd=bl;
        s0 += rd_; q0 += rd_*rd_; mn0 = fminf(mn0,r); mx0 = fmaxf(mx0,r);
        s1 += gd;  q1 += gd*gd;   mn1 = fminf(mn1,g); mx1 = fmaxf(mx1,g);
        s2 += bd;  q2 += bd*bd;   mn2 = fminf(mn2,bl); mx2 = fmaxf(mx2,bl);
        double lum = 0.299*rd_ + 0.587*gd + 0.114*bd;
        double d2 = lum*lum;
        l1 += lum; l2 += d2; l3 += d2*lum; l4 += d2*d2;
        if (lum < 0.2) dark += 1.0;
    }
    __shared__ double rd[256];
    __shared__ float  rf[256];
    double dv[11] = {s0,s1,s2,q0,q1,q2,l1,l2,l3,l4,dark};
    double dr[11];
    for (int q = 0; q < 11; ++q) {
        __syncthreads();
        rd[tid] = dv[q];
        __syncthreads();
        for (int st = 128; st > 0; st >>= 1) { if (tid < st) rd[tid] += rd[tid+st]; __syncthreads(); }
        dr[q] = rd[0];
    }
    float fv[6] = {mn0,mn1,mn2,mx0,mx1,mx2};
    float fr[6];
    for (int q = 0; q < 6; ++q) {
        __syncthreads();
        rf[tid] = fv[q];
        __syncthreads();
        if (q < 3) { for (int st=128; st>0; st>>=1){ if (tid<st) rf[tid]=fminf(rf[tid],rf[tid+st]); __syncthreads(); } }
        else       { for (int st=128; st>0; st>>=1){ if (tid<st) rf[tid]=fmaxf(rf[tid],rf[tid+st]); __syncthreads(); } }
        fr[q] = rf[0];
    }
    if (tid == 0) {
        const double n = 65536.0;
        double* f = feats + b*15;
        for (int c = 0; c < 3; ++c) {
            double su = dr[c], sq = dr[3+c];
            f[c]   = su/n;
            f[3+c] = sqrt((sq - su*su/n) / (n - 1.0));
            f[6+c] = (double)fr[c];
            f[9+c] = (double)fr[3+c];
        }
        double m1 = dr[6]/n, m2 = dr[7]/n, m3 = dr[8]/n, m4 = dr[9]/n;
        double mu2 = m2 - m1*m1;
        double mu3 = m3 - 3.0*m1*m2 + 2.0*m1*m1*m1;
        double mu4 = m4 - 4.0*m1*m3 + 6.0*m1*m1*m2 - 3.0*m1*m1*m1*m1;
        double sd = sqrt(mu2);
        f[12] = mu3 / (sd*sd*sd + 1e-6);
        f[13] = mu4 / (sd*sd*sd*sd + 1e-6);
        f[14] = dr[10] / n;
    }
}

// ---------------- stat MLP: 15 -> 128 (relu) -> 128, f64 ----------------
__global__ __launch_bounds__(128) void sfmlp_kernel(const double* __restrict__ feats,
    const float* __restrict__ w1, const float* __restrict__ b1,
    const float* __restrict__ w2, const float* __restrict__ b2,
    double* __restrict__ sf)
{
    int b = blockIdx.x, t = threadIdx.x;
    __shared__ double fs[15];
    __shared__ double hs[128];
    if (t < 15) fs[t] = feats[b*15 + t];
    __syncthreads();
    double h = (double)b1[t];
    for (int j = 0; j < 15; ++j) h += fs[j] * (double)w1[t*15 + j];
    hs[t] = fmax(h, 0.0);
    __syncthreads();
    double o = (double)b2[t];
    for (int j = 0; j < 128; ++j) o += hs[j] * (double)w2[t*128 + j];
    sf[b*128 + t] = o;
}

// ---------------- patch embedding gather-GEMM, f64 accum -> x64 ----------------
__global__ __launch_bounds__(256) void patch_gemm_kernel(const float* __restrict__ img,
    const float* __restrict__ w, const float* __restrict__ bias,
    const float* __restrict__ pos, const double* __restrict__ sf,
    double* __restrict__ xout)
{
    __shared__ double As[64][65];
    __shared__ double Ws[64][65];
    int tid = threadIdx.x;
    int tx = tid & 15, ty = tid >> 4;
    int m0 = blockIdx.x * 64, n0 = blockIdx.y * 64;
    int kk = tid & 63, rr = tid >> 6;
    double acc[4][4] = {};
    for (int k0 = 0; k0 < 768; k0 += 64) {
        int k = k0 + kk;
        int c = k >> 8, rem = k & 255;
        int py = rem >> 4, px = rem & 15;
        #pragma unroll
        for (int p = 0; p < 16; ++p) {
            int mm = p*4 + rr;
            int m = m0 + mm;
            int bb = m >> 8, pat = m & 255;
            int gy = pat >> 4, gx = pat & 15;
            As[mm][kk] = (double)img[(size_t)(bb*3 + c)*65536 + (size_t)(gy*16+py)*256 + gx*16 + px];
            Ws[kk][mm] = (double)w[(size_t)(n0+mm)*768 + k];
        }
        __syncthreads();
        for (int k2 = 0; k2 < 64; ++k2) {
            double a[4], wv[4];
            #pragma unroll
            for (int i=0;i<4;++i) a[i] = As[ty*4+i][k2];
            #pragma unroll
            for (int j=0;j<4;++j) wv[j] = Ws[k2][tx*4+j];
            #pragma unroll
            for (int i=0;i<4;++i)
                #pragma unroll
                for (int j=0;j<4;++j) acc[i][j] = fma(a[i], wv[j], acc[i][j]);
        }
        __syncthreads();
    }
    #pragma unroll
    for (int i=0;i<4;++i){
        int m = m0 + ty*4 + i;
        int bb = m >> 8, pat = m & 255;
        #pragma unroll
        for (int j=0;j<4;++j){
            int n = n0 + tx*4 + j;
            xout[(size_t)m*128 + n] = acc[i][j] + (double)bias[n] + (double)pos[pat*128+n] + sf[bb*128+n];
        }
    }
}

// ---------------- LayerNorm over D=128, f64 math, f32 out ----------------
__global__ __launch_bounds__(256) void ln_kernel(const double* __restrict__ x,
    const float* __restrict__ s, const float* __restrict__ bta, float* __restrict__ out)
{
    int tid = threadIdx.x;
    int lane = tid & 63, w = tid >> 6;
    int row = blockIdx.x*4 + w;
    double v0 = x[(size_t)row*128 + lane*2];
    double v1 = x[(size_t)row*128 + lane*2 + 1];
    double sum = v0 + v1, sq = v0*v0 + v1*v1;
    #pragma unroll
    for (int o = 32; o > 0; o >>= 1) { sum += __shfl_xor(sum, o); sq += __shfl_xor(sq, o); }
    double mean = sum * (1.0/128.0);
    double var  = sq  * (1.0/128.0) - mean*mean;
    double inv  = 1.0 / sqrt(var + 1e-5);
    float2 o2;
    o2.x = (float)((v0 - mean)*inv*(double)s[lane*2]   + (double)bta[lane*2]);
    o2.y = (float)((v1 - mean)*inv*(double)s[lane*2+1] + (double)bta[lane*2+1]);
    *(float2*)&out[(size_t)row*128 + lane*2] = o2;
}

// ---------------- GEMM: f32 in, f64 accum. epi 0=store f32, 1=x64 += (residual), 2=gelu->f32
__global__ __launch_bounds__(256) void gemm_kernel(const float* __restrict__ A, int lda,
    const float* __restrict__ W, const float* __restrict__ bias,
    float* __restrict__ Cf, double* __restrict__ Xres,
    int M, int N, int K, int epi)
{
    __shared__ double As[64][65];
    __shared__ double Ws[64][65];
    int tid = threadIdx.x;
    int tx = tid & 15, ty = tid >> 4;
    int m0 = blockIdx.x * 64, n0 = blockIdx.y * 64;
    int kk = tid & 63, rr = tid >> 6;
    double acc[4][4] = {};
    for (int k0 = 0; k0 < K; k0 += 64) {
        #pragma unroll
        for (int p = 0; p < 16; ++p) {
            int mm = p*4 + rr;
            As[mm][kk] = (double)A[(size_t)(m0+mm)*lda + k0 + kk];
            Ws[kk][mm] = (double)W[(size_t)(n0+mm)*K + k0 + kk];
        }
        __syncthreads();
        for (int k2 = 0; k2 < 64; ++k2) {
            double a[4], wv[4];
            #pragma unroll
            for (int i=0;i<4;++i) a[i] = As[ty*4+i][k2];
            #pragma unroll
            for (int j=0;j<4;++j) wv[j] = Ws[k2][tx*4+j];
            #pragma unroll
            for (int i=0;i<4;++i)
                #pragma unroll
                for (int j=0;j<4;++j) acc[i][j] = fma(a[i], wv[j], acc[i][j]);
        }
        __syncthreads();
    }
    #pragma unroll
    for (int i=0;i<4;++i){
        int m = m0 + ty*4 + i;
        #pragma unroll
        for (int j=0;j<4;++j){
            int n = n0 + tx*4 + j;
            double v = acc[i][j] + (double)bias[n];
            if (epi == 0) {
                Cf[(size_t)m*N + n] = (float)v;
            } else if (epi == 1) {
                Xres[(size_t)m*N + n] += v;
            } else {
                double g = 0.5*v*(1.0 + erf(v*0.70710678118654752440));
                Cf[(size_t)m*N + n] = (float)g;
            }
        }
    }
}

// ---------------- attention: one block per (b,head); writes result into q slots ----------------
__global__ __launch_bounds__(256, 1) void attn_kernel(float* __restrict__ qkv)
{
    __shared__ double Ks[256][33];
    __shared__ double Vs[256][33];
    int t = threadIdx.x;
    int b = blockIdx.x >> 2, h = blockIdx.x & 3;
    size_t rb = (size_t)(b*256 + t) * 384;
    const float* kp = qkv + rb + 128 + h*32;
    const float* vp = qkv + rb + 256 + h*32;
    #pragma unroll
    for (int i = 0; i < 32; ++i) { Ks[t][i] = (double)kp[i]; Vs[t][i] = (double)vp[i]; }
    double q[32];
    const float* qp = qkv + rb + h*32;
    #pragma unroll
    for (int i = 0; i < 32; ++i) q[i] = (double)qp[i];
    __syncthreads();
    double o[32];
    #pragma unroll
    for (int i = 0; i < 32; ++i) o[i] = 0.0;
    double m = -INFINITY, l = 0.0;
    const double scale = 0.17677669529663688110;  // 1/sqrt(32)
    for (int j = 0; j < 256; ++j) {
        double s = 0.0;
        #pragma unroll
        for (int i = 0; i < 32; ++i) s = fma(q[i], Ks[j][i], s);
        s *= scale;
        double mn = fmax(m, s);
        double f = exp(m - mn);
        double e = exp(s - mn);
        l = l*f + e;
        #pragma unroll
        for (int i = 0; i < 32; ++i) o[i] = fma(o[i], f, e*Vs[j][i]);
        m = mn;
    }
    double inv = 1.0 / l;
    float* op = qkv + rb + h*32;   // overwrite own q slot (only this block touches these cols)
    #pragma unroll
    for (int i = 0; i < 32; ++i) op[i] = (float)(o[i] * inv);
}

// ---------------- VQ replicating numpy-f32 semantics ----------------
// dist = fl32( fl32(zz + cc) - 2f*dot ), zz/cc = numpy pairwise-128 f32 sums,
// dot = sequential ascending-k f32 FMA (BLAS sgemm semantics). argmin first-index.
__global__ __launch_bounds__(256) void vq_kernel(const double* __restrict__ x,
    const float* __restrict__ cb, float* __restrict__ quant,
    float* __restrict__ idxf, float* __restrict__ counts)
{
    __shared__ float Zs[64][129];
    __shared__ float Cs[64][129];
    __shared__ float zzs[64];
    __shared__ float ccs[64];
    __shared__ float bvs[64][16];
    __shared__ int   bis[64][16];
    __shared__ int   fidx[64];
    int tid = threadIdx.x;
    int tx = tid & 15, ty = tid >> 4;
    int m0 = blockIdx.x * 64;
    for (int e = tid; e < 8192; e += 256) {
        int r = e >> 7, k = e & 127;
        Zs[r][k] = (float)x[(size_t)(m0+r)*128 + k];   // f32 z, matches np's stored f32 x
    }
    __syncthreads();
    if (tid < 64) {
        // numpy pairwise sum, n=128: 8 accumulators then paired combine
        float r[8];
        #pragma unroll
        for (int j = 0; j < 8; ++j) { float v = Zs[tid][j]; r[j] = v*v; }
        for (int i = 8; i < 128; i += 8)
            #pragma unroll
            for (int j = 0; j < 8; ++j) { float v = Zs[tid][i+j]; r[j] += v*v; }
        zzs[tid] = ((r[0]+r[1]) + (r[2]+r[3])) + ((r[4]+r[5]) + (r[6]+r[7]));
    }
    float bestv[4] = {INFINITY, INFINITY, INFINITY, INFINITY};
    int   besti[4] = {0,0,0,0};
    for (int t = 0; t < 8; ++t) {
        __syncthreads();
        for (int e = tid; e < 8192; e += 256) {
            int r = e >> 7, k = e & 127;
            Cs[r][k] = cb[(size_t)(t*64+r)*128 + k];
        }
        __syncthreads();
        if (tid < 64) {
            float r[8];
            #pragma unroll
            for (int j = 0; j < 8; ++j) { float v = Cs[tid][j]; r[j] = v*v; }
            for (int i = 8; i < 128; i += 8)
                #pragma unroll
                for (int j = 0; j < 8; ++j) { float v = Cs[tid][i+j]; r[j] += v*v; }
            ccs[tid] = ((r[0]+r[1]) + (r[2]+r[3])) + ((r[4]+r[5]) + (r[6]+r[7]));
        }
        __syncthreads();
        // dot: single f32 accumulator per (row,code), ascending k, FMA
        float acc[4][4] = {};
        for (int k = 0; k < 128; ++k) {
            float a[4], c[4];
            #pragma unroll
            for (int i=0;i<4;++i) a[i] = Zs[ty*4+i][k];
            #pragma unroll
            for (int j=0;j<4;++j) c[j] = Cs[tx*4+j][k];
            #pragma unroll
            for (int i=0;i<4;++i)
                #pragma unroll
                for (int j=0;j<4;++j) acc[i][j] = fmaf(a[i], c[j], acc[i][j]);
        }
        #pragma unroll
        for (int j = 0; j < 4; ++j) {
            float cc = ccs[tx*4+j];
            int code = t*64 + tx*4 + j;
            #pragma unroll
            for (int i = 0; i < 4; ++i) {
                float zz = zzs[ty*4+i];
                float t1 = zz + cc;              // f32 broadcast add (np order)
                float d  = t1 - 2.0f*acc[i][j];  // 2*acc exact; single-rounded subtract
                if (d < bestv[i]) { bestv[i] = d; besti[i] = code; }  // codes ascend -> first-index kept
            }
        }
    }
    #pragma unroll
    for (int i=0;i<4;++i){ bvs[ty*4+i][tx] = bestv[i]; bis[ty*4+i][tx] = besti[i]; }
    __syncthreads();
    if (tid < 64) {
        float v = bvs[tid][0]; int gi = bis[tid][0];
        for (int t2 = 1; t2 < 16; ++t2) {
            float vv = bvs[tid][t2]; int ii = bis[tid][t2];
            if (vv < v || (vv == v && ii < gi)) { v = vv; gi = ii; }
        }
        fidx[tid] = gi;
        idxf[m0 + tid] = (float)gi;
        atomicAdd(&counts[gi], 1.0f);
    }
    __syncthreads();
    for (int e = tid; e < 8192; e += 256) {
        int r = e >> 7, k = e & 127;
        quant[(size_t)(m0+r)*128 + k] = cb[(size_t)fidx[r]*128 + k];
    }
}

// ---------------- gf (mean over patches, f64) + logits ----------------
__global__ __launch_bounds__(128) void gf_logits_kernel(const float* __restrict__ quant,
    const float* __restrict__ head_w, const float* __restrict__ head_b,
    float* __restrict__ gf, float* __restrict__ logits)
{
    int b = blockIdx.x, d = threadIdx.x;
    double s = 0.0;
    for (int n = 0; n < 256; ++n) s += (double)quant[(size_t)(b*256+n)*128 + d];
    double g = s * (1.0/256.0);
    gf[b*128 + d] = (float)g;
    __shared__ double gs[128];
    gs[d] = g;
    __syncthreads();
    if (d < 8) {
        double l = (double)head_b[d];
        for (int k = 0; k < 128; ++k) l += gs[k] * (double)head_w[d*128 + k];
        logits[b*8 + d] = (float)l;
    }
}

// ---------------- perplexity, f64 ----------------
__global__ __launch_bounds__(512) void perp_kernel(const float* __restrict__ counts,
                                                   float* __restrict__ out)
{
    __shared__ double sh[512];
    int t = threadIdx.x;
    double p = (double)counts[t] * (1.0/16384.0);
    sh[t] = p * log(p + 1e-10);
    __syncthreads();
    for (int s = 256; s > 0; s >>= 1) { if (t < s) sh[t] += sh[t+s]; __syncthreads(); }
    if (t == 0) out[0] = (float)exp(-sh[0]);
}

extern "C" void kernel_launch(void* const* d_in, const int* in_sizes, int n_in,
                              void* d_out, int out_size, void* d_ws, size_t ws_size,
                              hipStream_t stream)
{
    const float* image   = (const float*)d_in[0];
    const float* conv_w  = (const float*)d_in[1];
    const float* conv_b  = (const float*)d_in[2];
    const float* stat_w1 = (const float*)d_in[3];
    const float* stat_b1 = (const float*)d_in[4];
    const float* stat_w2 = (const float*)d_in[5];
    const float* stat_b2 = (const float*)d_in[6];
    const float* pos     = (const float*)d_in[7];
    const float* ln1_s   = (const float*)d_in[8];
    const float* ln1_b   = (const float*)d_in[9];
    const float* qkv_w   = (const float*)d_in[10];
    const float* qkv_b   = (const float*)d_in[11];
    const float* out_w   = (const float*)d_in[12];
    const float* out_b   = (const float*)d_in[13];
    const float* ln2_s   = (const float*)d_in[14];
    const float* ln2_b   = (const float*)d_in[15];
    const float* ff1_w   = (const float*)d_in[16];
    const float* ff1_b   = (const float*)d_in[17];
    const float* ff2_w   = (const float*)d_in[18];
    const float* ff2_b   = (const float*)d_in[19];
    const float* codebook= (const float*)d_in[20];
    const float* head_w  = (const float*)d_in[21];
    const float* head_b  = (const float*)d_in[22];

    char* wsb = (char*)d_ws;
    double* x64   = (double*)wsb;                              // 16,777,216 B
    double* sf64  = (double*)(wsb + 16777216);                 // 65,536 B
    double* feats = (double*)(wsb + 16842752);                 // 7,680 B
    float*  counts= (float*) (wsb + 16850432);                 // 2,048 B
    float*  h32   = (float*) (wsb + 16852480);                 // 8,388,608 B
    float*  qkv32 = (float*) (wsb + 25241088);                 // 25,165,824 B

    float* outf   = (float*)d_out;
    float* quant  = outf;
    float* idxf   = quant + 2097152;
    float* logits = idxf + 16384;
    float* gf     = logits + 512;
    float* perp   = gf + 8192;

    hipMemsetAsync(counts, 0, 512*sizeof(float), stream);

    stats_kernel<<<64, 256, 0, stream>>>(image, feats);
    sfmlp_kernel<<<64, 128, 0, stream>>>(feats, stat_w1, stat_b1, stat_w2, stat_b2, sf64);
    patch_gemm_kernel<<<dim3(256, 2), 256, 0, stream>>>(image, conv_w, conv_b, pos, sf64, x64);

    for (int i = 0; i < 2; ++i) {
        ln_kernel<<<4096, 256, 0, stream>>>(x64, ln1_s + i*128, ln1_b + i*128, h32);
        gemm_kernel<<<dim3(256, 6), 256, 0, stream>>>(h32, 128, qkv_w + (size_t)i*384*128,
                                                      qkv_b + i*384, qkv32, nullptr,
                                                      16384, 384, 128, 0);
        attn_kernel<<<256, 256, 0, stream>>>(qkv32);
        gemm_kernel<<<dim3(256, 2), 256, 0, stream>>>(qkv32, 384, out_w + (size_t)i*128*128,
                                                      out_b + i*128, nullptr, x64,
                                                      16384, 128, 128, 1);
        ln_kernel<<<4096, 256, 0, stream>>>(x64, ln2_s + i*128, ln2_b + i*128, h32);
        gemm_kernel<<<dim3(256, 4), 256, 0, stream>>>(h32, 128, ff1_w + (size_t)i*256*128,
                                                      ff1_b + i*256, qkv32, nullptr,
                                                      16384, 256, 128, 2);
        gemm_kernel<<<dim3(256, 2), 256, 0, stream>>>(qkv32, 256, ff2_w + (size_t)i*128*256,
                                                      ff2_b + i*128, nullptr, x64,
                                                      16384, 128, 256, 1);
    }

    vq_kernel<<<256, 256, 0, stream>>>(x64, codebook, quant, idxf, counts);
    gf_logits_kernel<<<64, 128, 0, stream>>>(quant, head_w, head_b, gf, logits);
    perp_kernel<<<1, 512, 0, stream>>>(counts, perp);
}

// Round 4
// 713.015 us; speedup vs baseline: 1.7935x; 1.7935x over previous
//
#include <hip/hip_runtime.h>
#include <math.h>

// ---------------- stats (per-image 15 features, f64) ----------------
__global__ __launch_bounds__(256) void stats_kernel(const float* __restrict__ img,
                                                    double* __restrict__ feats)
{
    int b = blockIdx.x, tid = threadIdx.x;
    const float* r0 = img + (size_t)b * 3 * 65536;
    const float* g0 = r0 + 65536;
    const float* b0 = r0 + 131072;
    double s0=0,s1=0,s2=0, q0=0,q1=0,q2=0, l1=0,l2=0,l3=0,l4=0;
    float mn0=1e30f,mn1=1e30f,mn2=1e30f, mx0=-1e30f,mx1=-1e30f,mx2=-1e30f;
    double dark=0.0;
    for (int p = tid; p < 65536; p += 256) {
        float r = r0[p], g = g0[p], bl = b0[p];
        double rd_=r, gd=g, bd=bl;
        s0 += rd_; q0 += rd_*rd_; mn0 = fminf(mn0,r); mx0 = fmaxf(mx0,r);
        s1 += gd;  q1 += gd*gd;   mn1 = fminf(mn1,g); mx1 = fmaxf(mx1,g);
        s2 += bd;  q2 += bd*bd;   mn2 = fminf(mn2,bl); mx2 = fmaxf(mx2,bl);
        double lum = 0.299*rd_ + 0.587*gd + 0.114*bd;
        double d2 = lum*lum;
        l1 += lum; l2 += d2; l3 += d2*lum; l4 += d2*d2;
        if (lum < 0.2) dark += 1.0;
    }
    __shared__ double rd[256];
    __shared__ float  rf[256];
    double dv[11] = {s0,s1,s2,q0,q1,q2,l1,l2,l3,l4,dark};
    double dr[11];
    for (int q = 0; q < 11; ++q) {
        __syncthreads();
        rd[tid] = dv[q];
        __syncthreads();
        for (int st = 128; st > 0; st >>= 1) { if (tid < st) rd[tid] += rd[tid+st]; __syncthreads(); }
        dr[q] = rd[0];
    }
    float fv[6] = {mn0,mn1,mn2,mx0,mx1,mx2};
    float fr[6];
    for (int q = 0; q < 6; ++q) {
        __syncthreads();
        rf[tid] = fv[q];
        __syncthreads();
        if (q < 3) { for (int st=128; st>0; st>>=1){ if (tid<st) rf[tid]=fminf(rf[tid],rf[tid+st]); __syncthreads(); } }
        else       { for (int st=128; st>0; st>>=1){ if (tid<st) rf[tid]=fmaxf(rf[tid],rf[tid+st]); __syncthreads(); } }
        fr[q] = rf[0];
    }
    if (tid == 0) {
        const double n = 65536.0;
        double* f = feats + b*15;
        for (int c = 0; c < 3; ++c) {
            double su = dr[c], sq = dr[3+c];
            f[c]   = su/n;
            f[3+c] = sqrt((sq - su*su/n) / (n - 1.0));
            f[6+c] = (double)fr[c];
            f[9+c] = (double)fr[3+c];
        }
        double m1 = dr[6]/n, m2 = dr[7]/n, m3 = dr[8]/n, m4 = dr[9]/n;
        double mu2 = m2 - m1*m1;
        double mu3 = m3 - 3.0*m1*m2 + 2.0*m1*m1*m1;
        double mu4 = m4 - 4.0*m1*m3 + 6.0*m1*m1*m2 - 3.0*m1*m1*m1*m1;
        double sd = sqrt(mu2);
        f[12] = mu3 / (sd*sd*sd + 1e-6);
        f[13] = mu4 / (sd*sd*sd*sd + 1e-6);
        f[14] = dr[10] / n;
    }
}

// ---------------- stat MLP: 15 -> 128 (relu) -> 128, f64 ----------------
__global__ __launch_bounds__(128) void sfmlp_kernel(const double* __restrict__ feats,
    const float* __restrict__ w1, const float* __restrict__ b1,
    const float* __restrict__ w2, const float* __restrict__ b2,
    double* __restrict__ sf)
{
    int b = blockIdx.x, t = threadIdx.x;
    __shared__ double fs[15];
    __shared__ double hs[128];
    if (t < 15) fs[t] = feats[b*15 + t];
    __syncthreads();
    double h = (double)b1[t];
    for (int j = 0; j < 15; ++j) h += fs[j] * (double)w1[t*15 + j];
    hs[t] = fmax(h, 0.0);
    __syncthreads();
    double o = (double)b2[t];
    for (int j = 0; j < 128; ++j) o += hs[j] * (double)w2[t*128 + j];
    sf[b*128 + t] = o;
}

// XOR-swizzled LDS tile: 64 rows x 64 cols f32, flat 4096.
// element (r,k) lives at r*64 + ((k>>2 ^ (r&15))<<2) + (k&3)
__device__ __forceinline__ int swz64(int r, int kq4) { // kq4 = quad index 0..15
    return r*64 + (((kq4) ^ (r & 15)) << 2);
}

// ---------------- patch embedding gather-GEMM, f32 -> x32 ----------------
__global__ __launch_bounds__(256) void patch_gemm_kernel(const float* __restrict__ img,
    const float* __restrict__ w, const float* __restrict__ bias,
    const float* __restrict__ pos, const double* __restrict__ sf,
    float* __restrict__ xout)
{
    __shared__ float As[4096];
    __shared__ float Ws[4096];
    int tid = threadIdx.x;
    int tx = tid & 15, ty = tid >> 4;
    int m0 = blockIdx.x * 64, n0 = blockIdx.y * 64;
    int kq = tid & 15;        // k-quad 0..15
    int r0 = tid >> 4;        // 0..15
    float acc[4][4] = {};
    for (int k0 = 0; k0 < 768; k0 += 64) {
        #pragma unroll
        for (int p = 0; p < 4; ++p) {
            int row = p*16 + r0;
            int m = m0 + row;
            int bb = m >> 8, pat = m & 255;
            int gy = pat >> 4, gx = pat & 15;
            int k = k0 + kq*4;
            int c = k >> 8, rem = k & 255;
            int py = rem >> 4, px = rem & 15;
            float4 av = *(const float4*)&img[(size_t)(bb*3 + c)*65536 + (size_t)(gy*16+py)*256 + gx*16 + px];
            *(float4*)&As[swz64(row, kq)] = av;
            float4 wv = *(const float4*)&w[(size_t)(n0+row)*768 + k];
            *(float4*)&Ws[swz64(row, kq)] = wv;
        }
        __syncthreads();
        #pragma unroll 8
        for (int q = 0; q < 16; ++q) {
            float4 a4[4], w4[4];
            #pragma unroll
            for (int i=0;i<4;++i) a4[i] = *(const float4*)&As[swz64(ty + 16*i, q)];
            #pragma unroll
            for (int j=0;j<4;++j) w4[j] = *(const float4*)&Ws[swz64(tx + 16*j, q)];
            #pragma unroll
            for (int i=0;i<4;++i)
                #pragma unroll
                for (int j=0;j<4;++j) {
                    acc[i][j] = fmaf(a4[i].x, w4[j].x, acc[i][j]);
                    acc[i][j] = fmaf(a4[i].y, w4[j].y, acc[i][j]);
                    acc[i][j] = fmaf(a4[i].z, w4[j].z, acc[i][j]);
                    acc[i][j] = fmaf(a4[i].w, w4[j].w, acc[i][j]);
                }
        }
        __syncthreads();
    }
    #pragma unroll
    for (int i=0;i<4;++i){
        int m = m0 + ty + 16*i;
        int bb = m >> 8, pat = m & 255;
        #pragma unroll
        for (int j=0;j<4;++j){
            int n = n0 + tx + 16*j;
            float v = acc[i][j] + bias[n];
            v += pos[pat*128 + n];
            v += (float)sf[bb*128 + n];
            xout[(size_t)m*128 + n] = v;
        }
    }
}

// ---------------- LayerNorm over D=128 (f32 io, f64 internal) ----------------
__global__ __launch_bounds__(256) void ln_kernel(const float* __restrict__ x,
    const float* __restrict__ s, const float* __restrict__ bta, float* __restrict__ out)
{
    int tid = threadIdx.x;
    int lane = tid & 63, w = tid >> 6;
    int row = blockIdx.x*4 + w;
    float2 v = *(const float2*)&x[(size_t)row*128 + lane*2];
    double v0 = v.x, v1 = v.y;
    double sum = v0 + v1, sq = v0*v0 + v1*v1;
    #pragma unroll
    for (int o = 32; o > 0; o >>= 1) { sum += __shfl_xor(sum, o); sq += __shfl_xor(sq, o); }
    double mean = sum * (1.0/128.0);
    double var  = sq  * (1.0/128.0) - mean*mean;
    double inv  = 1.0 / sqrt(var + 1e-5);
    float2 o2;
    o2.x = (float)((v0 - mean)*inv*(double)s[lane*2]   + (double)bta[lane*2]);
    o2.y = (float)((v1 - mean)*inv*(double)s[lane*2+1] + (double)bta[lane*2+1]);
    *(float2*)&out[(size_t)row*128 + lane*2] = o2;
}

// ---------------- f32 GEMM: C = A(MxK) @ W(NxK)^T + bias ----------------
// epi: 0=store f32, 1=Xres += v (residual), 2=gelu(exact)->f32
__global__ __launch_bounds__(256) void gemm_kernel(const float* __restrict__ A, int lda,
    const float* __restrict__ W, const float* __restrict__ bias,
    float* __restrict__ C, float* __restrict__ Xres,
    int M, int N, int K, int epi)
{
    __shared__ float As[4096];
    __shared__ float Ws[4096];
    int tid = threadIdx.x;
    int tx = tid & 15, ty = tid >> 4;
    int m0 = blockIdx.x * 64, n0 = blockIdx.y * 64;
    int kq = tid & 15;
    int r0 = tid >> 4;
    float acc[4][4] = {};
    for (int k0 = 0; k0 < K; k0 += 64) {
        #pragma unroll
        for (int p = 0; p < 4; ++p) {
            int row = p*16 + r0;
            float4 av = *(const float4*)&A[(size_t)(m0+row)*lda + k0 + kq*4];
            *(float4*)&As[swz64(row, kq)] = av;
            float4 wv = *(const float4*)&W[(size_t)(n0+row)*K + k0 + kq*4];
            *(float4*)&Ws[swz64(row, kq)] = wv;
        }
        __syncthreads();
        #pragma unroll 8
        for (int q = 0; q < 16; ++q) {
            float4 a4[4], w4[4];
            #pragma unroll
            for (int i=0;i<4;++i) a4[i] = *(const float4*)&As[swz64(ty + 16*i, q)];
            #pragma unroll
            for (int j=0;j<4;++j) w4[j] = *(const float4*)&Ws[swz64(tx + 16*j, q)];
            #pragma unroll
            for (int i=0;i<4;++i)
                #pragma unroll
                for (int j=0;j<4;++j) {
                    acc[i][j] = fmaf(a4[i].x, w4[j].x, acc[i][j]);
                    acc[i][j] = fmaf(a4[i].y, w4[j].y, acc[i][j]);
                    acc[i][j] = fmaf(a4[i].z, w4[j].z, acc[i][j]);
                    acc[i][j] = fmaf(a4[i].w, w4[j].w, acc[i][j]);
                }
        }
        __syncthreads();
    }
    #pragma unroll
    for (int i=0;i<4;++i){
        int m = m0 + ty + 16*i;
        #pragma unroll
        for (int j=0;j<4;++j){
            int n = n0 + tx + 16*j;
            float v = acc[i][j] + bias[n];
            if (epi == 0) {
                C[(size_t)m*N + n] = v;
            } else if (epi == 1) {
                Xres[(size_t)m*N + n] += v;
            } else {
                C[(size_t)m*N + n] = 0.5f*v*(1.0f + erff(v*0.70710678118654752f));
            }
        }
    }
}

// ---------------- attention: one block per (b,head), f32 flash per-thread row ----------------
__global__ __launch_bounds__(256) void attn_kernel(float* __restrict__ qkv)
{
    __shared__ float Ks[256*36];
    __shared__ float Vs[256*36];
    int t = threadIdx.x;
    int b = blockIdx.x >> 2, h = blockIdx.x & 3;
    size_t rb = (size_t)(b*256 + t) * 384;
    const float* kp = qkv + rb + 128 + h*32;
    const float* vp = qkv + rb + 256 + h*32;
    #pragma unroll
    for (int i = 0; i < 8; ++i) {
        *(float4*)&Ks[t*36 + i*4] = *(const float4*)&kp[i*4];
        *(float4*)&Vs[t*36 + i*4] = *(const float4*)&vp[i*4];
    }
    float q[32];
    const float* qp = qkv + rb + h*32;
    #pragma unroll
    for (int i = 0; i < 32; ++i) q[i] = qp[i];
    __syncthreads();
    float o[32];
    #pragma unroll
    for (int i = 0; i < 32; ++i) o[i] = 0.f;
    float m = -INFINITY, l = 0.f;
    const float scale = 0.17677669529663687f;  // 1/sqrt(32)
    for (int j = 0; j < 256; ++j) {
        const float* kr = &Ks[j*36];
        float s = 0.f;
        #pragma unroll
        for (int i = 0; i < 32; ++i) s = fmaf(q[i], kr[i], s);
        s *= scale;
        const float* vr = &Vs[j*36];
        if (__all(s <= m)) {           // no row in this wave updates its max: f==1 path
            float e = expf(s - m);
            l += e;
            #pragma unroll
            for (int i = 0; i < 32; ++i) o[i] = fmaf(e, vr[i], o[i]);
        } else {
            float mn = fmaxf(m, s);
            float f = expf(m - mn);
            float e = expf(s - mn);
            l = l*f + e;
            #pragma unroll
            for (int i = 0; i < 32; ++i) o[i] = fmaf(o[i], f, e*vr[i]);
            m = mn;
        }
    }
    float inv = 1.0f / l;
    float* op = qkv + rb + h*32;   // overwrite own q slot
    #pragma unroll
    for (int i = 0; i < 32; ++i) op[i] = o[i] * inv;
}

// ---------------- VQ replicating numpy-f32 semantics (dist rounding bit-matched) ----------------
// element (r,k) of a 64x128 tile at r*128 + ((k>>2 ^ (r&15))<<2) + (k&3)
__device__ __forceinline__ int vqswz(int r, int k) {
    return r*128 + ((((k >> 2) ^ (r & 15)) << 2) | (k & 3));
}
__device__ __forceinline__ int vqswzq(int r, int kq4) {  // quad-aligned
    return r*128 + (((kq4) ^ (r & 15)) << 2);
}

__global__ __launch_bounds__(256) void vq_kernel(const float* __restrict__ x,
    const float* __restrict__ cb, float* __restrict__ quant,
    float* __restrict__ idxf, float* __restrict__ counts)
{
    __shared__ float Zs[8192];
    __shared__ float Cs[8192];
    __shared__ float zzs[64];
    __shared__ float ccs[64];
    __shared__ float bvs[64][16];
    __shared__ int   bis[64][16];
    __shared__ int   fidx[64];
    int tid = threadIdx.x;
    int tx = tid & 15, ty = tid >> 4;
    int m0 = blockIdx.x * 64;
    int kq = tid & 31;        // k-quad 0..31
    int r5 = tid >> 5;        // 0..7
    #pragma unroll
    for (int p = 0; p < 8; ++p) {
        int row = p*8 + r5;
        float4 zv = *(const float4*)&x[(size_t)(m0+row)*128 + kq*4];
        *(float4*)&Zs[vqswzq(row, kq)] = zv;
    }
    __syncthreads();
    if (tid < 64) {
        // numpy pairwise sum, n=128: 8 accumulators then paired combine
        float r[8];
        #pragma unroll
        for (int j = 0; j < 8; ++j) { float v = Zs[vqswz(tid, j)]; r[j] = v*v; }
        for (int i = 8; i < 128; i += 8)
            #pragma unroll
            for (int j = 0; j < 8; ++j) { float v = Zs[vqswz(tid, i+j)]; r[j] += v*v; }
        zzs[tid] = ((r[0]+r[1]) + (r[2]+r[3])) + ((r[4]+r[5]) + (r[6]+r[7]));
    }
    float bestv[4] = {INFINITY, INFINITY, INFINITY, INFINITY};
    int   besti[4] = {0,0,0,0};
    for (int t = 0; t < 8; ++t) {
        __syncthreads();
        #pragma unroll
        for (int p = 0; p < 8; ++p) {
            int row = p*8 + r5;
            float4 cv = *(const float4*)&cb[(size_t)(t*64+row)*128 + kq*4];
            *(float4*)&Cs[vqswzq(row, kq)] = cv;
        }
        __syncthreads();
        if (tid < 64) {
            float r[8];
            #pragma unroll
            for (int j = 0; j < 8; ++j) { float v = Cs[vqswz(tid, j)]; r[j] = v*v; }
            for (int i = 8; i < 128; i += 8)
                #pragma unroll
                for (int j = 0; j < 8; ++j) { float v = Cs[vqswz(tid, i+j)]; r[j] += v*v; }
            ccs[tid] = ((r[0]+r[1]) + (r[2]+r[3])) + ((r[4]+r[5]) + (r[6]+r[7]));
        }
        __syncthreads();
        // dot: single f32 accumulator per (row,code), ascending k, FMA (BLAS semantics)
        float acc[4][4] = {};
        #pragma unroll 8
        for (int q = 0; q < 32; ++q) {
            float4 a4[4], c4[4];
            #pragma unroll
            for (int i=0;i<4;++i) a4[i] = *(const float4*)&Zs[vqswzq(ty + 16*i, q)];
            #pragma unroll
            for (int j=0;j<4;++j) c4[j] = *(const float4*)&Cs[vqswzq(tx + 16*j, q)];
            #pragma unroll
            for (int i=0;i<4;++i)
                #pragma unroll
                for (int j=0;j<4;++j) {
                    acc[i][j] = fmaf(a4[i].x, c4[j].x, acc[i][j]);
                    acc[i][j] = fmaf(a4[i].y, c4[j].y, acc[i][j]);
                    acc[i][j] = fmaf(a4[i].z, c4[j].z, acc[i][j]);
                    acc[i][j] = fmaf(a4[i].w, c4[j].w, acc[i][j]);
                }
        }
        #pragma unroll
        for (int j = 0; j < 4; ++j) {
            float cc = ccs[tx + 16*j];
            int code = t*64 + tx + 16*j;
            #pragma unroll
            for (int i = 0; i < 4; ++i) {
                float zz = zzs[ty + 16*i];
                float t1 = zz + cc;              // f32 broadcast add (np order)
                float d  = t1 - 2.0f*acc[i][j];  // single-rounded subtract
                if (d < bestv[i]) { bestv[i] = d; besti[i] = code; }  // codes ascend per thread
            }
        }
    }
    #pragma unroll
    for (int i=0;i<4;++i){ bvs[ty + 16*i][tx] = bestv[i]; bis[ty + 16*i][tx] = besti[i]; }
    __syncthreads();
    if (tid < 64) {
        float v = bvs[tid][0]; int gi = bis[tid][0];
        for (int t2 = 1; t2 < 16; ++t2) {
            float vv = bvs[tid][t2]; int ii = bis[tid][t2];
            if (vv < v || (vv == v && ii < gi)) { v = vv; gi = ii; }
        }
        fidx[tid] = gi;
        idxf[m0 + tid] = (float)gi;
        atomicAdd(&counts[gi], 1.0f);
    }
    __syncthreads();
    for (int e = tid; e < 8192; e += 256) {
        int r = e >> 7, k = e & 127;
        quant[(size_t)(m0+r)*128 + k] = cb[(size_t)fidx[r]*128 + k];
    }
}

// ---------------- gf (mean over patches, f64) + logits ----------------
__global__ __launch_bounds__(128) void gf_logits_kernel(const float* __restrict__ quant,
    const float* __restrict__ head_w, const float* __restrict__ head_b,
    float* __restrict__ gf, float* __restrict__ logits)
{
    int b = blockIdx.x, d = threadIdx.x;
    double s = 0.0;
    for (int n = 0; n < 256; ++n) s += (double)quant[(size_t)(b*256+n)*128 + d];
    double g = s * (1.0/256.0);
    gf[b*128 + d] = (float)g;
    __shared__ double gs[128];
    gs[d] = g;
    __syncthreads();
    if (d < 8) {
        double l = (double)head_b[d];
        for (int k = 0; k < 128; ++k) l += gs[k] * (double)head_w[d*128 + k];
        logits[b*8 + d] = (float)l;
    }
}

// ---------------- perplexity, f64 ----------------
__global__ __launch_bounds__(512) void perp_kernel(const float* __restrict__ counts,
                                                   float* __restrict__ out)
{
    __shared__ double sh[512];
    int t = threadIdx.x;
    double p = (double)counts[t] * (1.0/16384.0);
    sh[t] = p * log(p + 1e-10);
    __syncthreads();
    for (int s = 256; s > 0; s >>= 1) { if (t < s) sh[t] += sh[t+s]; __syncthreads(); }
    if (t == 0) out[0] = (float)exp(-sh[0]);
}

extern "C" void kernel_launch(void* const* d_in, const int* in_sizes, int n_in,
                              void* d_out, int out_size, void* d_ws, size_t ws_size,
                              hipStream_t stream)
{
    const float* image   = (const float*)d_in[0];
    const float* conv_w  = (const float*)d_in[1];
    const float* conv_b  = (const float*)d_in[2];
    const float* stat_w1 = (const float*)d_in[3];
    const float* stat_b1 = (const float*)d_in[4];
    const float* stat_w2 = (const float*)d_in[5];
    const float* stat_b2 = (const float*)d_in[6];
    const float* pos     = (const float*)d_in[7];
    const float* ln1_s   = (const float*)d_in[8];
    const float* ln1_b   = (const float*)d_in[9];
    const float* qkv_w   = (const float*)d_in[10];
    const float* qkv_b   = (const float*)d_in[11];
    const float* out_w   = (const float*)d_in[12];
    const float* out_b   = (const float*)d_in[13];
    const float* ln2_s   = (const float*)d_in[14];
    const float* ln2_b   = (const float*)d_in[15];
    const float* ff1_w   = (const float*)d_in[16];
    const float* ff1_b   = (const float*)d_in[17];
    const float* ff2_w   = (const float*)d_in[18];
    const float* ff2_b   = (const float*)d_in[19];
    const float* codebook= (const float*)d_in[20];
    const float* head_w  = (const float*)d_in[21];
    const float* head_b  = (const float*)d_in[22];

    char* wsb = (char*)d_ws;
    float*  x32   = (float*) (wsb);                            //  8,388,608 B
    float*  h32   = (float*) (wsb + 8388608);                  //  8,388,608 B
    float*  qkv32 = (float*) (wsb + 16777216);                 // 25,165,824 B
    double* sf64  = (double*)(wsb + 41943040);                 //     65,536 B
    double* feats = (double*)(wsb + 42008576);                 //      7,680 B
    float*  counts= (float*) (wsb + 42016256);                 //      2,048 B

    float* outf   = (float*)d_out;
    float* quant  = outf;
    float* idxf   = quant + 2097152;
    float* logits = idxf + 16384;
    float* gf     = logits + 512;
    float* perp   = gf + 8192;

    hipMemsetAsync(counts, 0, 512*sizeof(float), stream);

    stats_kernel<<<64, 256, 0, stream>>>(image, feats);
    sfmlp_kernel<<<64, 128, 0, stream>>>(feats, stat_w1, stat_b1, stat_w2, stat_b2, sf64);
    patch_gemm_kernel<<<dim3(256, 2), 256, 0, stream>>>(image, conv_w, conv_b, pos, sf64, x32);

    for (int i = 0; i < 2; ++i) {
        ln_kernel<<<4096, 256, 0, stream>>>(x32, ln1_s + i*128, ln1_b + i*128, h32);
        gemm_kernel<<<dim3(256, 6), 256, 0, stream>>>(h32, 128, qkv_w + (size_t)i*384*128,
                                                      qkv_b + i*384, qkv32, nullptr,
                                                      16384, 384, 128, 0);
        attn_kernel<<<256, 256, 0, stream>>>(qkv32);
        gemm_kernel<<<dim3(256, 2), 256, 0, stream>>>(qkv32, 384, out_w + (size_t)i*128*128,
                                                      out_b + i*128, nullptr, x32,
                                                      16384, 128, 128, 1);
        ln_kernel<<<4096, 256, 0, stream>>>(x32, ln2_s + i*128, ln2_b + i*128, h32);
        gemm_kernel<<<dim3(256, 4), 256, 0, stream>>>(h32, 128, ff1_w + (size_t)i*256*128,
                                                      ff1_b + i*256, qkv32, nullptr,
                                                      16384, 256, 128, 2);
        gemm_kernel<<<dim3(256, 2), 256, 0, stream>>>(qkv32, 256, ff2_w + (size_t)i*128*256,
                                                      ff2_b + i*128, nullptr, x32,
                                                      16384, 128, 256, 1);
    }

    vq_kernel<<<256, 256, 0, stream>>>(x32, codebook, quant, idxf, counts);
    gf_logits_kernel<<<64, 128, 0, stream>>>(quant, head_w, head_b, gf, logits);
    perp_kernel<<<1, 512, 0, stream>>>(counts, perp);
}

// Round 5
// 626.024 us; speedup vs baseline: 2.0427x; 1.1390x over previous
//
#include <hip/hip_runtime.h>
#include <math.h>

// ---------------- stats phase 1: per-(image, 1/32-slice) partials ----------------
__device__ __forceinline__ double wred_add(double v) {
    #pragma unroll
    for (int o = 32; o > 0; o >>= 1) v += __shfl_xor(v, o);
    return v;
}
__device__ __forceinline__ float wred_min(float v) {
    #pragma unroll
    for (int o = 32; o > 0; o >>= 1) v = fminf(v, __shfl_xor(v, o));
    return v;
}
__device__ __forceinline__ float wred_max(float v) {
    #pragma unroll
    for (int o = 32; o > 0; o >>= 1) v = fmaxf(v, __shfl_xor(v, o));
    return v;
}

// partial record: 17 doubles: s0,s1,s2,q0,q1,q2,l1,l2,l3,l4,dark,mn0,mn1,mn2,mx0,mx1,mx2
#define PREC 17

__global__ __launch_bounds__(256) void stats_partial_kernel(const float* __restrict__ img,
                                                            double* __restrict__ part)
{
    int b = blockIdx.x >> 5, blk = blockIdx.x & 31;
    int tid = threadIdx.x;
    const float* r0 = img + (size_t)b * 3 * 65536;
    const float* g0 = r0 + 65536;
    const float* b0 = r0 + 131072;
    int base = blk*2048 + tid*8;
    double s0=0,s1=0,s2=0,q0=0,q1=0,q2=0,l1=0,l2=0,l3=0,l4=0,dark=0;
    float mn0=1e30f,mn1=1e30f,mn2=1e30f, mx0=-1e30f,mx1=-1e30f,mx2=-1e30f;
    #pragma unroll
    for (int u = 0; u < 2; ++u) {
        float4 rv = *(const float4*)&r0[base + u*4];
        float4 gv = *(const float4*)&g0[base + u*4];
        float4 bv = *(const float4*)&b0[base + u*4];
        float rr[4] = {rv.x, rv.y, rv.z, rv.w};
        float gg[4] = {gv.x, gv.y, gv.z, gv.w};
        float bbv[4] = {bv.x, bv.y, bv.z, bv.w};
        #pragma unroll
        for (int e = 0; e < 4; ++e) {
            float r = rr[e], g = gg[e], bl = bbv[e];
            double rd_ = r, gd = g, bd = bl;
            s0 += rd_; q0 += rd_*rd_; mn0 = fminf(mn0, r); mx0 = fmaxf(mx0, r);
            s1 += gd;  q1 += gd*gd;   mn1 = fminf(mn1, g); mx1 = fmaxf(mx1, g);
            s2 += bd;  q2 += bd*bd;   mn2 = fminf(mn2, bl); mx2 = fmaxf(mx2, bl);
            double lum = 0.299*rd_ + 0.587*gd + 0.114*bd;
            double d2 = lum*lum;
            l1 += lum; l2 += d2; l3 += d2*lum; l4 += d2*d2;
            if (lum < 0.2) dark += 1.0;
        }
    }
    double dv[11] = {s0,s1,s2,q0,q1,q2,l1,l2,l3,l4,dark};
    #pragma unroll
    for (int q = 0; q < 11; ++q) dv[q] = wred_add(dv[q]);
    mn0 = wred_min(mn0); mn1 = wred_min(mn1); mn2 = wred_min(mn2);
    mx0 = wred_max(mx0); mx1 = wred_max(mx1); mx2 = wred_max(mx2);
    __shared__ double sd[4][PREC];
    int w = tid >> 6, lane = tid & 63;
    if (lane == 0) {
        #pragma unroll
        for (int q = 0; q < 11; ++q) sd[w][q] = dv[q];
        sd[w][11] = (double)mn0; sd[w][12] = (double)mn1; sd[w][13] = (double)mn2;
        sd[w][14] = (double)mx0; sd[w][15] = (double)mx1; sd[w][16] = (double)mx2;
    }
    __syncthreads();
    if (tid == 0) {
        double out[PREC];
        #pragma unroll
        for (int q = 0; q < PREC; ++q) out[q] = sd[0][q];
        #pragma unroll
        for (int ww = 1; ww < 4; ++ww) {
            #pragma unroll
            for (int q = 0; q < 11; ++q) out[q] += sd[ww][q];
            out[11] = fmin(out[11], sd[ww][11]); out[12] = fmin(out[12], sd[ww][12]);
            out[13] = fmin(out[13], sd[ww][13]);
            out[14] = fmax(out[14], sd[ww][14]); out[15] = fmax(out[15], sd[ww][15]);
            out[16] = fmax(out[16], sd[ww][16]);
        }
        double* p = part + (size_t)(b*32 + blk)*PREC;
        #pragma unroll
        for (int q = 0; q < PREC; ++q) p[q] = out[q];
    }
}

// ---------------- stats phase 2: combine 32 partials -> 15 feats ----------------
__global__ __launch_bounds__(32) void stats_final_kernel(const double* __restrict__ part,
                                                         double* __restrict__ feats)
{
    int b = blockIdx.x, t = threadIdx.x;   // t = 0..31
    const double* p = part + (size_t)(b*32 + t)*PREC;
    double v[PREC];
    #pragma unroll
    for (int q = 0; q < PREC; ++q) v[q] = p[q];
    #pragma unroll
    for (int o = 16; o > 0; o >>= 1) {
        #pragma unroll
        for (int q = 0; q < 11; ++q) v[q] += __shfl_xor(v[q], o);
        #pragma unroll
        for (int q = 11; q < 14; ++q) v[q] = fmin(v[q], __shfl_xor(v[q], o));
        #pragma unroll
        for (int q = 14; q < PREC; ++q) v[q] = fmax(v[q], __shfl_xor(v[q], o));
    }
    if (t == 0) {
        const double n = 65536.0;
        double* f = feats + b*15;
        for (int c = 0; c < 3; ++c) {
            double su = v[c], sq = v[3+c];
            f[c]   = su/n;
            f[3+c] = sqrt((sq - su*su/n) / (n - 1.0));
            f[6+c] = v[11+c];
            f[9+c] = v[14+c];
        }
        double m1 = v[6]/n, m2 = v[7]/n, m3 = v[8]/n, m4 = v[9]/n;
        double mu2 = m2 - m1*m1;
        double mu3 = m3 - 3.0*m1*m2 + 2.0*m1*m1*m1;
        double mu4 = m4 - 4.0*m1*m3 + 6.0*m1*m1*m2 - 3.0*m1*m1*m1*m1;
        double sd = sqrt(mu2);
        f[12] = mu3 / (sd*sd*sd + 1e-6);
        f[13] = mu4 / (sd*sd*sd*sd + 1e-6);
        f[14] = v[10] / n;
    }
}

// ---------------- stat MLP: 15 -> 128 (relu) -> 128, f64 ----------------
__global__ __launch_bounds__(128) void sfmlp_kernel(const double* __restrict__ feats,
    const float* __restrict__ w1, const float* __restrict__ b1,
    const float* __restrict__ w2, const float* __restrict__ b2,
    double* __restrict__ sf)
{
    int b = blockIdx.x, t = threadIdx.x;
    __shared__ double fs[15];
    __shared__ double hs[128];
    if (t < 15) fs[t] = feats[b*15 + t];
    __syncthreads();
    double h = (double)b1[t];
    for (int j = 0; j < 15; ++j) h += fs[j] * (double)w1[t*15 + j];
    hs[t] = fmax(h, 0.0);
    __syncthreads();
    double o = (double)b2[t];
    for (int j = 0; j < 128; ++j) o += hs[j] * (double)w2[t*128 + j];
    sf[b*128 + t] = o;
}

// XOR-swizzled LDS tile: 64 rows x 64 cols f32, flat 4096.
__device__ __forceinline__ int swz64(int r, int kq4) {
    return r*64 + (((kq4) ^ (r & 15)) << 2);
}

// ---------------- patch embedding gather-GEMM, f32 -> x32 ----------------
__global__ __launch_bounds__(256) void patch_gemm_kernel(const float* __restrict__ img,
    const float* __restrict__ w, const float* __restrict__ bias,
    const float* __restrict__ pos, const double* __restrict__ sf,
    float* __restrict__ xout)
{
    __shared__ float As[4096];
    __shared__ float Ws[4096];
    int tid = threadIdx.x;
    int tx = tid & 15, ty = tid >> 4;
    int m0 = blockIdx.x * 64, n0 = blockIdx.y * 64;
    int kq = tid & 15;
    int r0 = tid >> 4;
    float acc[4][4] = {};
    for (int k0 = 0; k0 < 768; k0 += 64) {
        #pragma unroll
        for (int p = 0; p < 4; ++p) {
            int row = p*16 + r0;
            int m = m0 + row;
            int bb = m >> 8, pat = m & 255;
            int gy = pat >> 4, gx = pat & 15;
            int k = k0 + kq*4;
            int c = k >> 8, rem = k & 255;
            int py = rem >> 4, px = rem & 15;
            float4 av = *(const float4*)&img[(size_t)(bb*3 + c)*65536 + (size_t)(gy*16+py)*256 + gx*16 + px];
            *(float4*)&As[swz64(row, kq)] = av;
            float4 wv = *(const float4*)&w[(size_t)(n0+row)*768 + k];
            *(float4*)&Ws[swz64(row, kq)] = wv;
        }
        __syncthreads();
        #pragma unroll 8
        for (int q = 0; q < 16; ++q) {
            float4 a4[4], w4[4];
            #pragma unroll
            for (int i=0;i<4;++i) a4[i] = *(const float4*)&As[swz64(ty + 16*i, q)];
            #pragma unroll
            for (int j=0;j<4;++j) w4[j] = *(const float4*)&Ws[swz64(tx + 16*j, q)];
            #pragma unroll
            for (int i=0;i<4;++i)
                #pragma unroll
                for (int j=0;j<4;++j) {
                    acc[i][j] = fmaf(a4[i].x, w4[j].x, acc[i][j]);
                    acc[i][j] = fmaf(a4[i].y, w4[j].y, acc[i][j]);
                    acc[i][j] = fmaf(a4[i].z, w4[j].z, acc[i][j]);
                    acc[i][j] = fmaf(a4[i].w, w4[j].w, acc[i][j]);
                }
        }
        __syncthreads();
    }
    #pragma unroll
    for (int i=0;i<4;++i){
        int m = m0 + ty + 16*i;
        int bb = m >> 8, pat = m & 255;
        #pragma unroll
        for (int j=0;j<4;++j){
            int n = n0 + tx + 16*j;
            float v = acc[i][j] + bias[n];
            v += pos[pat*128 + n];
            v += (float)sf[bb*128 + n];
            xout[(size_t)m*128 + n] = v;
        }
    }
}

// ---------------- LayerNorm over D=128 (f32 io, f64 internal) ----------------
__global__ __launch_bounds__(256) void ln_kernel(const float* __restrict__ x,
    const float* __restrict__ s, const float* __restrict__ bta, float* __restrict__ out)
{
    int tid = threadIdx.x;
    int lane = tid & 63, w = tid >> 6;
    int row = blockIdx.x*4 + w;
    float2 v = *(const float2*)&x[(size_t)row*128 + lane*2];
    double v0 = v.x, v1 = v.y;
    double sum = v0 + v1, sq = v0*v0 + v1*v1;
    #pragma unroll
    for (int o = 32; o > 0; o >>= 1) { sum += __shfl_xor(sum, o); sq += __shfl_xor(sq, o); }
    double mean = sum * (1.0/128.0);
    double var  = sq  * (1.0/128.0) - mean*mean;
    double inv  = 1.0 / sqrt(var + 1e-5);
    float2 o2;
    o2.x = (float)((v0 - mean)*inv*(double)s[lane*2]   + (double)bta[lane*2]);
    o2.y = (float)((v1 - mean)*inv*(double)s[lane*2+1] + (double)bta[lane*2+1]);
    *(float2*)&out[(size_t)row*128 + lane*2] = o2;
}

// ---------------- f32 GEMM: C = A(MxK) @ W(NxK)^T + bias ----------------
__global__ __launch_bounds__(256) void gemm_kernel(const float* __restrict__ A, int lda,
    const float* __restrict__ W, const float* __restrict__ bias,
    float* __restrict__ C, float* __restrict__ Xres,
    int M, int N, int K, int epi)
{
    __shared__ float As[4096];
    __shared__ float Ws[4096];
    int tid = threadIdx.x;
    int tx = tid & 15, ty = tid >> 4;
    int m0 = blockIdx.x * 64, n0 = blockIdx.y * 64;
    int kq = tid & 15;
    int r0 = tid >> 4;
    float acc[4][4] = {};
    for (int k0 = 0; k0 < K; k0 += 64) {
        #pragma unroll
        for (int p = 0; p < 4; ++p) {
            int row = p*16 + r0;
            float4 av = *(const float4*)&A[(size_t)(m0+row)*lda + k0 + kq*4];
            *(float4*)&As[swz64(row, kq)] = av;
            float4 wv = *(const float4*)&W[(size_t)(n0+row)*K + k0 + kq*4];
            *(float4*)&Ws[swz64(row, kq)] = wv;
        }
        __syncthreads();
        #pragma unroll 8
        for (int q = 0; q < 16; ++q) {
            float4 a4[4], w4[4];
            #pragma unroll
            for (int i=0;i<4;++i) a4[i] = *(const float4*)&As[swz64(ty + 16*i, q)];
            #pragma unroll
            for (int j=0;j<4;++j) w4[j] = *(const float4*)&Ws[swz64(tx + 16*j, q)];
            #pragma unroll
            for (int i=0;i<4;++i)
                #pragma unroll
                for (int j=0;j<4;++j) {
                    acc[i][j] = fmaf(a4[i].x, w4[j].x, acc[i][j]);
                    acc[i][j] = fmaf(a4[i].y, w4[j].y, acc[i][j]);
                    acc[i][j] = fmaf(a4[i].z, w4[j].z, acc[i][j]);
                    acc[i][j] = fmaf(a4[i].w, w4[j].w, acc[i][j]);
                }
        }
        __syncthreads();
    }
    #pragma unroll
    for (int i=0;i<4;++i){
        int m = m0 + ty + 16*i;
        #pragma unroll
        for (int j=0;j<4;++j){
            int n = n0 + tx + 16*j;
            float v = acc[i][j] + bias[n];
            if (epi == 0) {
                C[(size_t)m*N + n] = v;
            } else if (epi == 1) {
                Xres[(size_t)m*N + n] += v;
            } else {
                C[(size_t)m*N + n] = 0.5f*v*(1.0f + erff(v*0.70710678118654752f));
            }
        }
    }
}

// ---------------- attention: one block per (b, head), f32 flash per-thread row ----------------
__global__ __launch_bounds__(256) void attn_kernel(float* __restrict__ qkv)
{
    __shared__ float Ks[256*36];
    __shared__ float Vs[256*36];
    int t = threadIdx.x;
    int b = blockIdx.x >> 2, h = blockIdx.x & 3;
    size_t rb = (size_t)(b*256 + t) * 384;
    const float* kp = qkv + rb + 128 + h*32;
    const float* vp = qkv + rb + 256 + h*32;
    #pragma unroll
    for (int i = 0; i < 8; ++i) {
        *(float4*)&Ks[t*36 + i*4] = *(const float4*)&kp[i*4];
        *(float4*)&Vs[t*36 + i*4] = *(const float4*)&vp[i*4];
    }
    float q[32];
    const float* qp = qkv + rb + h*32;
    #pragma unroll
    for (int i = 0; i < 32; ++i) q[i] = qp[i];
    __syncthreads();
    float o[32];
    #pragma unroll
    for (int i = 0; i < 32; ++i) o[i] = 0.f;
    float m = -INFINITY, l = 0.f;
    const float scale = 0.17677669529663687f;
    for (int j = 0; j < 256; ++j) {
        const float* kr = &Ks[j*36];
        float s = 0.f;
        #pragma unroll
        for (int i = 0; i < 32; ++i) s = fmaf(q[i], kr[i], s);
        s *= scale;
        const float* vr = &Vs[j*36];
        if (__all(s <= m)) {
            float e = expf(s - m);
            l += e;
            #pragma unroll
            for (int i = 0; i < 32; ++i) o[i] = fmaf(e, vr[i], o[i]);
        } else {
            float mn = fmaxf(m, s);
            float f = expf(m - mn);
            float e = expf(s - mn);
            l = l*f + e;
            #pragma unroll
            for (int i = 0; i < 32; ++i) o[i] = fmaf(o[i], f, e*vr[i]);
            m = mn;
        }
    }
    float inv = 1.0f / l;
    float* op = qkv + rb + h*32;
    #pragma unroll
    for (int i = 0; i < 32; ++i) op[i] = o[i] * inv;
}

// ---------------- VQ replicating numpy-f32 semantics ----------------
__device__ __forceinline__ int vqswz(int r, int k) {
    return r*128 + ((((k >> 2) ^ (r & 15)) << 2) | (k & 3));
}
__device__ __forceinline__ int vqswzq(int r, int kq4) {
    return r*128 + (((kq4) ^ (r & 15)) << 2);
}

__global__ __launch_bounds__(256) void vq_kernel(const float* __restrict__ x,
    const float* __restrict__ cb, float* __restrict__ quant,
    float* __restrict__ idxf, float* __restrict__ counts)
{
    __shared__ float Zs[8192];
    __shared__ float Cs[8192];
    __shared__ float zzs[64];
    __shared__ float ccs[64];
    __shared__ float bvs[64][16];
    __shared__ int   bis[64][16];
    __shared__ int   fidx[64];
    int tid = threadIdx.x;
    int tx = tid & 15, ty = tid >> 4;
    int m0 = blockIdx.x * 64;
    int kq = tid & 31;
    int r5 = tid >> 5;
    #pragma unroll
    for (int p = 0; p < 8; ++p) {
        int row = p*8 + r5;
        float4 zv = *(const float4*)&x[(size_t)(m0+row)*128 + kq*4];
        *(float4*)&Zs[vqswzq(row, kq)] = zv;
    }
    __syncthreads();
    if (tid < 64) {
        float r[8];
        #pragma unroll
        for (int j = 0; j < 8; ++j) { float v = Zs[vqswz(tid, j)]; r[j] = v*v; }
        for (int i = 8; i < 128; i += 8)
            #pragma unroll
            for (int j = 0; j < 8; ++j) { float v = Zs[vqswz(tid, i+j)]; r[j] += v*v; }
        zzs[tid] = ((r[0]+r[1]) + (r[2]+r[3])) + ((r[4]+r[5]) + (r[6]+r[7]));
    }
    float bestv[4] = {INFINITY, INFINITY, INFINITY, INFINITY};
    int   besti[4] = {0,0,0,0};
    for (int t = 0; t < 8; ++t) {
        __syncthreads();
        #pragma unroll
        for (int p = 0; p < 8; ++p) {
            int row = p*8 + r5;
            float4 cv = *(const float4*)&cb[(size_t)(t*64+row)*128 + kq*4];
            *(float4*)&Cs[vqswzq(row, kq)] = cv;
        }
        __syncthreads();
        if (tid < 64) {
            float r[8];
            #pragma unroll
            for (int j = 0; j < 8; ++j) { float v = Cs[vqswz(tid, j)]; r[j] = v*v; }
            for (int i = 8; i < 128; i += 8)
                #pragma unroll
                for (int j = 0; j < 8; ++j) { float v = Cs[vqswz(tid, i+j)]; r[j] += v*v; }
            ccs[tid] = ((r[0]+r[1]) + (r[2]+r[3])) + ((r[4]+r[5]) + (r[6]+r[7]));
        }
        __syncthreads();
        float acc[4][4] = {};
        #pragma unroll 8
        for (int q = 0; q < 32; ++q) {
            float4 a4[4], c4[4];
            #pragma unroll
            for (int i=0;i<4;++i) a4[i] = *(const float4*)&Zs[vqswzq(ty + 16*i, q)];
            #pragma unroll
            for (int j=0;j<4;++j) c4[j] = *(const float4*)&Cs[vqswzq(tx + 16*j, q)];
            #pragma unroll
            for (int i=0;i<4;++i)
                #pragma unroll
                for (int j=0;j<4;++j) {
                    acc[i][j] = fmaf(a4[i].x, c4[j].x, acc[i][j]);
                    acc[i][j] = fmaf(a4[i].y, c4[j].y, acc[i][j]);
                    acc[i][j] = fmaf(a4[i].z, c4[j].z, acc[i][j]);
                    acc[i][j] = fmaf(a4[i].w, c4[j].w, acc[i][j]);
                }
        }
        #pragma unroll
        for (int j = 0; j < 4; ++j) {
            float cc = ccs[tx + 16*j];
            int code = t*64 + tx + 16*j;
            #pragma unroll
            for (int i = 0; i < 4; ++i) {
                float zz = zzs[ty + 16*i];
                float t1 = zz + cc;
                float d  = t1 - 2.0f*acc[i][j];
                if (d < bestv[i]) { bestv[i] = d; besti[i] = code; }
            }
        }
    }
    #pragma unroll
    for (int i=0;i<4;++i){ bvs[ty + 16*i][tx] = bestv[i]; bis[ty + 16*i][tx] = besti[i]; }
    __syncthreads();
    if (tid < 64) {
        float v = bvs[tid][0]; int gi = bis[tid][0];
        for (int t2 = 1; t2 < 16; ++t2) {
            float vv = bvs[tid][t2]; int ii = bis[tid][t2];
            if (vv < v || (vv == v && ii < gi)) { v = vv; gi = ii; }
        }
        fidx[tid] = gi;
        idxf[m0 + tid] = (float)gi;
        atomicAdd(&counts[gi], 1.0f);
    }
    __syncthreads();
    for (int e = tid; e < 8192; e += 256) {
        int r = e >> 7, k = e & 127;
        quant[(size_t)(m0+r)*128 + k] = cb[(size_t)fidx[r]*128 + k];
    }
}

// ---------------- gf (mean over patches, f64) + logits ----------------
__global__ __launch_bounds__(128) void gf_logits_kernel(const float* __restrict__ quant,
    const float* __restrict__ head_w, const float* __restrict__ head_b,
    float* __restrict__ gf, float* __restrict__ logits)
{
    int b = blockIdx.x, d = threadIdx.x;
    double s = 0.0;
    for (int n = 0; n < 256; ++n) s += (double)quant[(size_t)(b*256+n)*128 + d];
    double g = s * (1.0/256.0);
    gf[b*128 + d] = (float)g;
    __shared__ double gs[128];
    gs[d] = g;
    __syncthreads();
    if (d < 8) {
        double l = (double)head_b[d];
        for (int k = 0; k < 128; ++k) l += gs[k] * (double)head_w[d*128 + k];
        logits[b*8 + d] = (float)l;
    }
}

// ---------------- perplexity, f64 ----------------
__global__ __launch_bounds__(512) void perp_kernel(const float* __restrict__ counts,
                                                   float* __restrict__ out)
{
    __shared__ double sh[512];
    int t = threadIdx.x;
    double p = (double)counts[t] * (1.0/16384.0);
    sh[t] = p * log(p + 1e-10);
    __syncthreads();
    for (int s = 256; s > 0; s >>= 1) { if (t < s) sh[t] += sh[t+s]; __syncthreads(); }
    if (t == 0) out[0] = (float)exp(-sh[0]);
}

extern "C" void kernel_launch(void* const* d_in, const int* in_sizes, int n_in,
                              void* d_out, int out_size, void* d_ws, size_t ws_size,
                              hipStream_t stream)
{
    const float* image   = (const float*)d_in[0];
    const float* conv_w  = (const float*)d_in[1];
    const float* conv_b  = (const float*)d_in[2];
    const float* stat_w1 = (const float*)d_in[3];
    const float* stat_b1 = (const float*)d_in[4];
    const float* stat_w2 = (const float*)d_in[5];
    const float* stat_b2 = (const float*)d_in[6];
    const float* pos     = (const float*)d_in[7];
    const float* ln1_s   = (const float*)d_in[8];
    const float* ln1_b   = (const float*)d_in[9];
    const float* qkv_w   = (const float*)d_in[10];
    const float* qkv_b   = (const float*)d_in[11];
    const float* out_w   = (const float*)d_in[12];
    const float* out_b   = (const float*)d_in[13];
    const float* ln2_s   = (const float*)d_in[14];
    const float* ln2_b   = (const float*)d_in[15];
    const float* ff1_w   = (const float*)d_in[16];
    const float* ff1_b   = (const float*)d_in[17];
    const float* ff2_w   = (const float*)d_in[18];
    const float* ff2_b   = (const float*)d_in[19];
    const float* codebook= (const float*)d_in[20];
    const float* head_w  = (const float*)d_in[21];
    const float* head_b  = (const float*)d_in[22];

    char* wsb = (char*)d_ws;
    float*  x32   = (float*) (wsb);                            //  8,388,608 B
    float*  h32   = (float*) (wsb + 8388608);                  //  8,388,608 B
    float*  qkv32 = (float*) (wsb + 16777216);                 // 25,165,824 B
    double* sf64  = (double*)(wsb + 41943040);                 //     65,536 B
    double* feats = (double*)(wsb + 42008576);                 //      7,680 B
    float*  counts= (float*) (wsb + 42016256);                 //      2,048 B
    double* part  = (double*)(wsb + 42018304);                 // 2048*17*8 = 278,528 B

    float* outf   = (float*)d_out;
    float* quant  = outf;
    float* idxf   = quant + 2097152;
    float* logits = idxf + 16384;
    float* gf     = logits + 512;
    float* perp   = gf + 8192;

    hipMemsetAsync(counts, 0, 512*sizeof(float), stream);

    stats_partial_kernel<<<2048, 256, 0, stream>>>(image, part);
    stats_final_kernel<<<64, 32, 0, stream>>>(part, feats);
    sfmlp_kernel<<<64, 128, 0, stream>>>(feats, stat_w1, stat_b1, stat_w2, stat_b2, sf64);
    patch_gemm_kernel<<<dim3(256, 2), 256, 0, stream>>>(image, conv_w, conv_b, pos, sf64, x32);

    for (int i = 0; i < 2; ++i) {
        ln_kernel<<<4096, 256, 0, stream>>>(x32, ln1_s + i*128, ln1_b + i*128, h32);
        gemm_kernel<<<dim3(256, 6), 256, 0, stream>>>(h32, 128, qkv_w + (size_t)i*384*128,
                                                      qkv_b + i*384, qkv32, nullptr,
                                                      16384, 384, 128, 0);
        attn_kernel<<<256, 256, 0, stream>>>(qkv32);
        gemm_kernel<<<dim3(256, 2), 256, 0, stream>>>(qkv32, 384, out_w + (size_t)i*128*128,
                                                      out_b + i*128, nullptr, x32,
                                                      16384, 128, 128, 1);
        ln_kernel<<<4096, 256, 0, stream>>>(x32, ln2_s + i*128, ln2_b + i*128, h32);
        gemm_kernel<<<dim3(256, 4), 256, 0, stream>>>(h32, 128, ff1_w + (size_t)i*256*128,
                                                      ff1_b + i*256, qkv32, nullptr,
                                                      16384, 256, 128, 2);
        gemm_kernel<<<dim3(256, 2), 256, 0, stream>>>(qkv32, 256, ff2_w + (size_t)i*128*256,
                                                      ff2_b + i*128, nullptr, x32,
                                                      16384, 128, 256, 1);
    }

    vq_kernel<<<256, 256, 0, stream>>>(x32, codebook, quant, idxf, counts);
    gf_logits_kernel<<<64, 128, 0, stream>>>(quant, head_w, head_b, gf, logits);
    perp_kernel<<<1, 512, 0, stream>>>(counts, perp);
}